// Round 1
// baseline (615.371 us; speedup 1.0000x reference)
//
#include <hip/hip_runtime.h>

#define SS 304
#define HH 228
#define WW 304
#define FARV 100.0f
#define EPSV 1e-07f

// ---------------- Kernel 1: vertex transform -> NDC ----------------
__global__ __launch_bounds__(256) void xform_kernel(
    const float* __restrict__ verts,
    const float* __restrict__ Km,
    const float* __restrict__ Rm,
    const float* __restrict__ tm,
    float* __restrict__ ndc, int N)
{
#pragma clang fp contract(off)
    int n = blockIdx.x * blockDim.x + threadIdx.x;
    if (n >= N) return;
    float u = verts[3*n+0], v = verts[3*n+1], d = verts[3*n+2];
    float fx = Km[0], cx = Km[2], fy = Km[4], cy = Km[5];
    // K^-1 via triangular solve (matches LAPACK/XLA route): divisions
    float ki00 = 1.0f / fx;
    float ki02 = -(cx / fx);
    float ki11 = 1.0f / fy;
    float ki12 = -(cy / fy);
    float px = u * (float)WW;
    float py = v * (float)HH;
    // cam = (Kinv @ pix) * d
    float c0 = (ki00 * px + ki02) * d;
    float c1 = (ki11 * py + ki12) * d;
    float c2 = d;
    // cam2 = R @ cam + t
    float r0 = ((Rm[0]*c0 + Rm[1]*c1) + Rm[2]*c2) + tm[0];
    float r1 = ((Rm[3]*c0 + Rm[4]*c1) + Rm[5]*c2) + tm[1];
    float r2 = ((Rm[6]*c0 + Rm[7]*c1) + Rm[8]*c2) + tm[2];
    float z = r2;
    float zd = z + EPSV;
    float p0 = r0 / zd;
    float p1 = r1 / zd;
    // p @ K^T rows:  q0 = p0*fx + cx ; q1 = p1*fy + cy
    float q0 = p0 * fx + cx;
    float q1 = p1 * fy + cy;
    float uu = q0 / (float)WW; uu = fminf(fmaxf(uu, 0.0f), 1.0f);
    float vv = q1 / (float)HH; vv = fminf(fmaxf(vv, 0.0f), 1.0f);
    // ndc: ((u*W)/S)*2-1, ((v*H)/S)*2-1 (exact reference op order)
    float xn = uu * (float)WW / (float)SS * 2.0f - 1.0f;
    float yn = vv * (float)HH / (float)SS * 2.0f - 1.0f;
    ndc[3*n+0] = xn;
    ndc[3*n+1] = yn;
    ndc[3*n+2] = z;
}

// ---------------- Kernel 2: face gather + precompute ----------------
__global__ __launch_bounds__(256) void face_kernel(
    const float* __restrict__ ndc,
    const int* __restrict__ faces,
    float4* __restrict__ rec, int M)
{
#pragma clang fp contract(off)
    int m = blockIdx.x * blockDim.x + threadIdx.x;
    if (m >= M) return;
    int i0 = faces[3*m+0], i1 = faces[3*m+1], i2 = faces[3*m+2];
    float x0 = ndc[3*i0+0], y0 = ndc[3*i0+1], z0 = ndc[3*i0+2];
    float x1 = ndc[3*i1+0], y1 = ndc[3*i1+1], z1 = ndc[3*i1+2];
    float x2 = ndc[3*i2+0], y2 = ndc[3*i2+1], z2 = ndc[3*i2+2];
    float A0 = y1 - y2;          // (y1-y2)
    float B0 = x2 - x1;          // (x2-x1)
    float A1 = y2 - y0;          // (y2-y0)
    float B1 = x0 - x2;          // (x0-x2)
    float dy02 = y0 - y2;
    float denom = A0 * B1 + B0 * dy02;   // reference op order
    bool ok = fabsf(denom) > 1e-10f;
    float safe = ok ? denom : 1.0f;
    float xmin = fminf(x0, fminf(x1, x2)) - 1e-4f;
    float xmax = fmaxf(x0, fmaxf(x1, x2)) + 1e-4f;
    float ymin = fminf(y0, fminf(y1, y2)) - 1e-4f;
    float ymax = fmaxf(y0, fmaxf(y1, y2)) + 1e-4f;
    rec[4*m+0] = make_float4(A0, B0, A1, B1);
    rec[4*m+1] = make_float4(x2, y2, safe, ok ? 1.0f : 0.0f);
    rec[4*m+2] = make_float4(z0, z1, z2, 0.0f);
    rec[4*m+3] = make_float4(xmin, xmax, ymin, ymax);
}

// ---------------- Kernel 3: rasterize kept crop ----------------
__global__ __launch_bounds__(256) void raster_kernel(
    const float4* __restrict__ rec,
    float* __restrict__ out, int M)
{
#pragma clang fp contract(off)
    int w = blockIdx.x * 16 + threadIdx.x;
    int h = blockIdx.y * 16 + threadIdx.y;
    if (h >= HH) return;            // no barriers used; safe early exit
    int irow = SS - 1 - h;          // output row h = raster row S-1-h (flip)
    float XP = ((float)(2*w    + 1 - SS)) / (float)SS;
    float YP = ((float)(2*irow + 1 - SS)) / (float)SS;

    // tile bounds in NDC for block-uniform bbox culling
    int wlo = blockIdx.x * 16;
    int whi = min(wlo + 15, WW - 1);
    int hlo = blockIdx.y * 16;
    int hhi = min(hlo + 15, HH - 1);
    float txlo = ((float)(2*wlo + 1 - SS)) / (float)SS;
    float txhi = ((float)(2*whi + 1 - SS)) / (float)SS;
    float tylo = ((float)(2*(SS-1-hhi) + 1 - SS)) / (float)SS;
    float tyhi = ((float)(2*(SS-1-hlo) + 1 - SS)) / (float)SS;

    float depth = FARV;
    float sil = 0.0f;

    for (int m = 0; m < M; ++m) {
        float4 rb = rec[4*m+3];   // xmin,xmax,ymin,ymax
        if (rb.x > txhi || rb.y < txlo || rb.z > tyhi || rb.w < tylo) continue;
        float4 rA = rec[4*m+0];   // A0,B0,A1,B1
        float4 rB = rec[4*m+1];   // x2,y2,safe,okflag
        if (rB.w == 0.0f) continue;

        float nx = XP - rB.x;
        float ny = YP - rB.y;
        float n0 = rA.x * nx + rA.y * ny;
        float n1 = rA.z * nx + rA.w * ny;
        float s  = rB.z;

        // conservative sign tests (accept-on-doubt) to skip the divisions
        bool c0 = (n0 * s >= 0.0f) || (fabsf(n0) <= 1e-30f);
        bool c1 = (n1 * s >= 0.0f) || (fabsf(n1) <= 1e-30f);
        float q  = s - n0 - n1;
        float qs = (s >= 0.0f) ? q : -q;
        float mgn = 1e-5f * (fabsf(s) + fabsf(n0) + fabsf(n1)) + 1e-30f;
        bool c2 = qs >= -mgn;
        if (!(c0 && c1 && c2)) continue;

        // exact path — reproduces reference f32 arithmetic op-for-op
        float w0 = n0 / s;
        float w1 = n1 / s;
        float w2 = (1.0f - w0) - w1;
        if (!((w0 >= 0.0f) && (w1 >= 0.0f) && (w2 >= 0.0f))) continue;
        sil = 1.0f;
        float4 rZ = rec[4*m+2];   // z0,z1,z2
        float iz = (w0 / rZ.x + w1 / rZ.y) + w2 / rZ.z;
        float zden = (fabsf(iz) > EPSV) ? iz : EPSV;
        float zp = 1.0f / zden;
        float zc = (zp > 0.0f) ? zp : FARV;
        depth = fminf(depth, zc);
    }

    out[h * WW + w] = depth;
    out[HH * WW + h * WW + w] = sil;
}

extern "C" void kernel_launch(void* const* d_in, const int* in_sizes, int n_in,
                              void* d_out, int out_size, void* d_ws, size_t ws_size,
                              hipStream_t stream) {
    const float* verts = (const float*)d_in[0];
    const int*   faces = (const int*)d_in[1];
    const float* K     = (const float*)d_in[2];
    const float* R     = (const float*)d_in[3];
    const float* t     = (const float*)d_in[4];
    float* out = (float*)d_out;

    int N = in_sizes[0] / 3;   // 8192
    int M = in_sizes[1] / 3;   // 2048

    float*  ndc = (float*)d_ws;
    float4* rec = (float4*)((char*)d_ws + (size_t)N * 3 * sizeof(float));

    xform_kernel<<<(N + 255) / 256, 256, 0, stream>>>(verts, K, R, t, ndc, N);
    face_kernel<<<(M + 255) / 256, 256, 0, stream>>>(ndc, faces, rec, M);

    dim3 blk(16, 16);
    dim3 grd((WW + 15) / 16, (HH + 15) / 16);
    raster_kernel<<<grd, blk, 0, stream>>>(rec, out, M);
}

// Round 2
// 151.634 us; speedup vs baseline: 4.0583x; 4.0583x over previous
//
#include <hip/hip_runtime.h>

#define SS 304
#define HH 228
#define WW 304
#define FARV 100.0f
#define EPSV 1e-07f
#define SPLIT 8          // face-range slices (gridDim.z)
#define CH 256           // faces per slice == one staging chunk

// ---------------- Kernel 1: vertex transform -> NDC ----------------
__global__ __launch_bounds__(256) void xform_kernel(
    const float* __restrict__ verts,
    const float* __restrict__ Km,
    const float* __restrict__ Rm,
    const float* __restrict__ tm,
    float* __restrict__ ndc, int N)
{
#pragma clang fp contract(off)
    int n = blockIdx.x * blockDim.x + threadIdx.x;
    if (n >= N) return;
    float u = verts[3*n+0], v = verts[3*n+1], d = verts[3*n+2];
    float fx = Km[0], cx = Km[2], fy = Km[4], cy = Km[5];
    float ki00 = 1.0f / fx;
    float ki02 = -(cx / fx);
    float ki11 = 1.0f / fy;
    float ki12 = -(cy / fy);
    float px = u * (float)WW;
    float py = v * (float)HH;
    float c0 = (ki00 * px + ki02) * d;
    float c1 = (ki11 * py + ki12) * d;
    float c2 = d;
    float r0 = ((Rm[0]*c0 + Rm[1]*c1) + Rm[2]*c2) + tm[0];
    float r1 = ((Rm[3]*c0 + Rm[4]*c1) + Rm[5]*c2) + tm[1];
    float r2 = ((Rm[6]*c0 + Rm[7]*c1) + Rm[8]*c2) + tm[2];
    float z = r2;
    float zd = z + EPSV;
    float p0 = r0 / zd;
    float p1 = r1 / zd;
    float q0 = p0 * fx + cx;
    float q1 = p1 * fy + cy;
    float uu = q0 / (float)WW; uu = fminf(fmaxf(uu, 0.0f), 1.0f);
    float vv = q1 / (float)HH; vv = fminf(fmaxf(vv, 0.0f), 1.0f);
    float xn = uu * (float)WW / (float)SS * 2.0f - 1.0f;
    float yn = vv * (float)HH / (float)SS * 2.0f - 1.0f;
    ndc[3*n+0] = xn;
    ndc[3*n+1] = yn;
    ndc[3*n+2] = z;
}

// ---------------- Kernel 2: face gather + precompute (SoA) ----------------
__global__ __launch_bounds__(256) void face_kernel(
    const float* __restrict__ ndc,
    const int* __restrict__ faces,
    float4* __restrict__ bboxArr,
    float4* __restrict__ Aarr,
    float4* __restrict__ Barr,
    float4* __restrict__ Zarr, int M)
{
#pragma clang fp contract(off)
    int m = blockIdx.x * blockDim.x + threadIdx.x;
    if (m >= M) return;
    int i0 = faces[3*m+0], i1 = faces[3*m+1], i2 = faces[3*m+2];
    float x0 = ndc[3*i0+0], y0 = ndc[3*i0+1], z0 = ndc[3*i0+2];
    float x1 = ndc[3*i1+0], y1 = ndc[3*i1+1], z1 = ndc[3*i1+2];
    float x2 = ndc[3*i2+0], y2 = ndc[3*i2+1], z2 = ndc[3*i2+2];
    float A0 = y1 - y2;
    float B0 = x2 - x1;
    float A1 = y2 - y0;
    float B1 = x0 - x2;
    float dy02 = y0 - y2;
    float denom = A0 * B1 + B0 * dy02;   // reference op order
    bool ok = fabsf(denom) > 1e-10f;
    float safe = ok ? denom : 1.0f;
    float xmin, xmax, ymin, ymax;
    if (ok) {
        xmin = fminf(x0, fminf(x1, x2)) - 1e-4f;
        xmax = fmaxf(x0, fmaxf(x1, x2)) + 1e-4f;
        ymin = fminf(y0, fminf(y1, y2)) - 1e-4f;
        ymax = fmaxf(y0, fmaxf(y1, y2)) + 1e-4f;
    } else {
        // degenerate: empty bbox so it never passes tile cull
        xmin = 1e30f; xmax = -1e30f; ymin = 1e30f; ymax = -1e30f;
    }
    bboxArr[m] = make_float4(xmin, xmax, ymin, ymax);
    Aarr[m]    = make_float4(A0, B0, A1, B1);
    Barr[m]    = make_float4(x2, y2, safe, 0.0f);
    Zarr[m]    = make_float4(z0, z1, z2, 0.0f);
}

// ---------------- Kernel 2b: init output (depth=FAR, sil=0) ----------------
__global__ __launch_bounds__(256) void init_kernel(float* __restrict__ out)
{
    int i = blockIdx.x * blockDim.x + threadIdx.x;
    if (i < HH * WW) {
        out[i] = FARV;
        out[HH * WW + i] = 0.0f;
    }
}

// ---------------- Kernel 3: rasterize (LDS-staged, face-sliced) ----------------
__global__ __launch_bounds__(256) void raster_kernel(
    const float4* __restrict__ bboxArr,
    const float4* __restrict__ Aarr,
    const float4* __restrict__ Barr,
    const float4* __restrict__ Zarr,
    float* __restrict__ out, int M)
{
#pragma clang fp contract(off)
    __shared__ float4 sA[CH];
    __shared__ float4 sB[CH];
    __shared__ float4 sZ[CH];
    __shared__ int sCount;

    int tx = threadIdx.x, ty = threadIdx.y;
    int tid = ty * 16 + tx;
    int w = blockIdx.x * 16 + tx;
    int h = blockIdx.y * 16 + ty;

    // tile bounds in NDC (block-uniform)
    int wlo = blockIdx.x * 16;
    int whi = min(wlo + 15, WW - 1);
    int hlo = blockIdx.y * 16;
    int hhi = min(hlo + 15, HH - 1);
    float txlo = ((float)(2*wlo + 1 - SS)) / (float)SS;
    float txhi = ((float)(2*whi + 1 - SS)) / (float)SS;
    float tylo = ((float)(2*(SS-1-hhi) + 1 - SS)) / (float)SS;
    float tyhi = ((float)(2*(SS-1-hlo) + 1 - SS)) / (float)SS;

    if (tid == 0) sCount = 0;
    __syncthreads();

    // cooperative staging: one face per thread, compact survivors into LDS
    int m = blockIdx.z * CH + tid;   // M == SPLIT*CH == 2048
    if (m < M) {
        float4 rb = bboxArr[m];
        bool pass = !(rb.x > txhi || rb.y < txlo || rb.z > tyhi || rb.w < tylo);
        if (pass) {
            int i = atomicAdd(&sCount, 1);
            sA[i] = Aarr[m];
            sB[i] = Barr[m];
            sZ[i] = Zarr[m];
        }
    }
    __syncthreads();
    int cnt = sCount;

    if (h < HH) {
        int irow = SS - 1 - h;                       // vertical flip
        float XP = ((float)(2*w    + 1 - SS)) / (float)SS;
        float YP = ((float)(2*irow + 1 - SS)) / (float)SS;

        float depth = FARV;
        float sil = 0.0f;

        for (int k = 0; k < cnt; ++k) {
            float4 rA = sA[k];
            float4 rB = sB[k];
            float nx = XP - rB.x;
            float ny = YP - rB.y;
            float n0 = rA.x * nx + rA.y * ny;
            float n1 = rA.z * nx + rA.w * ny;
            float s  = rB.z;

            // conservative accept-on-doubt pre-test (skips the IEEE divides)
            bool c0 = (n0 * s >= 0.0f) || (fabsf(n0) <= 1e-30f);
            bool c1 = (n1 * s >= 0.0f) || (fabsf(n1) <= 1e-30f);
            float q  = s - n0 - n1;
            float qs = (s >= 0.0f) ? q : -q;
            float mgn = 1e-5f * (fabsf(s) + fabsf(n0) + fabsf(n1)) + 1e-30f;
            bool c2 = qs >= -mgn;
            if (!(c0 && c1 && c2)) continue;

            // exact path — reference f32 arithmetic op-for-op
            float w0 = n0 / s;
            float w1 = n1 / s;
            float w2 = (1.0f - w0) - w1;
            if (!((w0 >= 0.0f) && (w1 >= 0.0f) && (w2 >= 0.0f))) continue;
            sil = 1.0f;
            float4 rZ = sZ[k];
            float iz = (w0 / rZ.x + w1 / rZ.y) + w2 / rZ.z;
            float zden = (fabsf(iz) > EPSV) ? iz : EPSV;
            float zp = 1.0f / zden;
            float zc = (zp > 0.0f) ? zp : FARV;
            depth = fminf(depth, zc);
        }

        // merge across face slices: positive-float bit patterns are
        // monotone under unsigned compare
        if (depth < FARV)
            atomicMin((unsigned int*)&out[h * WW + w], __float_as_uint(depth));
        if (sil > 0.0f)
            atomicMax((unsigned int*)&out[HH * WW + h * WW + w], __float_as_uint(sil));
    }
}

extern "C" void kernel_launch(void* const* d_in, const int* in_sizes, int n_in,
                              void* d_out, int out_size, void* d_ws, size_t ws_size,
                              hipStream_t stream) {
    const float* verts = (const float*)d_in[0];
    const int*   faces = (const int*)d_in[1];
    const float* K     = (const float*)d_in[2];
    const float* R     = (const float*)d_in[3];
    const float* t     = (const float*)d_in[4];
    float* out = (float*)d_out;

    int N = in_sizes[0] / 3;   // 8192
    int M = in_sizes[1] / 3;   // 2048

    char* ws = (char*)d_ws;
    float*  ndc  = (float*)ws;                 ws += (size_t)N * 3 * sizeof(float);
    float4* bbox = (float4*)ws;                ws += (size_t)M * sizeof(float4);
    float4* Aarr = (float4*)ws;                ws += (size_t)M * sizeof(float4);
    float4* Barr = (float4*)ws;                ws += (size_t)M * sizeof(float4);
    float4* Zarr = (float4*)ws;                ws += (size_t)M * sizeof(float4);

    xform_kernel<<<(N + 255) / 256, 256, 0, stream>>>(verts, K, R, t, ndc, N);
    face_kernel<<<(M + 255) / 256, 256, 0, stream>>>(ndc, faces, bbox, Aarr, Barr, Zarr, M);
    init_kernel<<<(HH * WW + 255) / 256, 256, 0, stream>>>(out);

    dim3 blk(16, 16);
    dim3 grd((WW + 15) / 16, (HH + 15) / 16, SPLIT);
    raster_kernel<<<grd, blk, 0, stream>>>(bbox, Aarr, Barr, Zarr, out, M);
}

// Round 3
// 107.484 us; speedup vs baseline: 5.7252x; 1.4108x over previous
//
#include <hip/hip_runtime.h>

#define SS 304
#define HH 228
#define WW 304
#define FARV 100.0f
#define EPSV 1e-07f
#define SPLIT 16         // face-range slices (gridDim.z)
#define CH 128           // faces per slice == one staging chunk

// ---------------- Kernel 1: vertex transform -> NDC ----------------
__global__ __launch_bounds__(256) void xform_kernel(
    const float* __restrict__ verts,
    const float* __restrict__ Km,
    const float* __restrict__ Rm,
    const float* __restrict__ tm,
    float* __restrict__ ndc, int N)
{
#pragma clang fp contract(off)
    int n = blockIdx.x * blockDim.x + threadIdx.x;
    if (n >= N) return;
    float u = verts[3*n+0], v = verts[3*n+1], d = verts[3*n+2];
    float fx = Km[0], cx = Km[2], fy = Km[4], cy = Km[5];
    float ki00 = 1.0f / fx;
    float ki02 = -(cx / fx);
    float ki11 = 1.0f / fy;
    float ki12 = -(cy / fy);
    float px = u * (float)WW;
    float py = v * (float)HH;
    float c0 = (ki00 * px + ki02) * d;
    float c1 = (ki11 * py + ki12) * d;
    float c2 = d;
    float r0 = ((Rm[0]*c0 + Rm[1]*c1) + Rm[2]*c2) + tm[0];
    float r1 = ((Rm[3]*c0 + Rm[4]*c1) + Rm[5]*c2) + tm[1];
    float r2 = ((Rm[6]*c0 + Rm[7]*c1) + Rm[8]*c2) + tm[2];
    float z = r2;
    float zd = z + EPSV;
    float p0 = r0 / zd;
    float p1 = r1 / zd;
    float q0 = p0 * fx + cx;
    float q1 = p1 * fy + cy;
    float uu = q0 / (float)WW; uu = fminf(fmaxf(uu, 0.0f), 1.0f);
    float vv = q1 / (float)HH; vv = fminf(fmaxf(vv, 0.0f), 1.0f);
    float xn = uu * (float)WW / (float)SS * 2.0f - 1.0f;
    float yn = vv * (float)HH / (float)SS * 2.0f - 1.0f;
    ndc[3*n+0] = xn;
    ndc[3*n+1] = yn;
    ndc[3*n+2] = z;
}

// ------ Kernel 2: output init (depth=FAR,sil=0) + face gather/precompute ------
__global__ __launch_bounds__(256) void face_init_kernel(
    const float* __restrict__ ndc,
    const int* __restrict__ faces,
    float4* __restrict__ bboxArr,
    float4* __restrict__ Aarr,
    float4* __restrict__ Barr,
    float4* __restrict__ RZarr,
    float* __restrict__ out, int M)
{
#pragma clang fp contract(off)
    int g = blockIdx.x * blockDim.x + threadIdx.x;
    if (g < HH * WW) {
        out[g] = FARV;
        out[HH * WW + g] = 0.0f;
    }
    if (g >= M) return;
    int m = g;
    int i0 = faces[3*m+0], i1 = faces[3*m+1], i2 = faces[3*m+2];
    float x0 = ndc[3*i0+0], y0 = ndc[3*i0+1], z0 = ndc[3*i0+2];
    float x1 = ndc[3*i1+0], y1 = ndc[3*i1+1], z1 = ndc[3*i1+2];
    float x2 = ndc[3*i2+0], y2 = ndc[3*i2+1], z2 = ndc[3*i2+2];
    float A0 = y1 - y2;
    float B0 = x2 - x1;
    float A1 = y2 - y0;
    float B1 = x0 - x2;
    float dy02 = y0 - y2;
    float denom = A0 * B1 + B0 * dy02;   // reference op order
    bool ok = fabsf(denom) > 1e-10f;
    float safe = ok ? denom : 1.0f;
    float xmin, xmax, ymin, ymax;
    if (ok) {
        xmin = fminf(x0, fminf(x1, x2)) - 1e-4f;
        xmax = fmaxf(x0, fmaxf(x1, x2)) + 1e-4f;
        ymin = fminf(y0, fminf(y1, y2)) - 1e-4f;
        ymax = fmaxf(y0, fmaxf(y1, y2)) + 1e-4f;
    } else {
        // degenerate: empty bbox -> never staged
        xmin = 1e30f; xmax = -1e30f; ymin = 1e30f; ymax = -1e30f;
    }
    bboxArr[m] = make_float4(xmin, xmax, ymin, ymax);
    Aarr[m]    = make_float4(A0, B0, A1, B1);
    Barr[m]    = make_float4(x2, y2, safe, 0.0f);
    // reciprocal z: value-only use (feeds depth magnitude, not decisions)
    RZarr[m]   = make_float4(1.0f / z0, 1.0f / z1, 1.0f / z2, 0.0f);
}

// ---------------- Kernel 3: rasterize (LDS-staged, face-sliced) ----------------
__global__ __launch_bounds__(256) void raster_kernel(
    const float4* __restrict__ bboxArr,
    const float4* __restrict__ Aarr,
    const float4* __restrict__ Barr,
    const float4* __restrict__ RZarr,
    float* __restrict__ out, int M)
{
#pragma clang fp contract(off)
    __shared__ float4 sA[CH];
    __shared__ float4 sB[CH];
    __shared__ float4 sRZ[CH];
    __shared__ int sCount;

    int tx = threadIdx.x, ty = threadIdx.y;
    int tid = ty * 16 + tx;
    int w = blockIdx.x * 16 + tx;
    int h = blockIdx.y * 16 + ty;

    // tile bounds in NDC (block-uniform)
    int wlo = blockIdx.x * 16;
    int whi = min(wlo + 15, WW - 1);
    int hlo = blockIdx.y * 16;
    int hhi = min(hlo + 15, HH - 1);
    float txlo = ((float)(2*wlo + 1 - SS)) / (float)SS;
    float txhi = ((float)(2*whi + 1 - SS)) / (float)SS;
    float tylo = ((float)(2*(SS-1-hhi) + 1 - SS)) / (float)SS;
    float tyhi = ((float)(2*(SS-1-hlo) + 1 - SS)) / (float)SS;

    if (tid == 0) sCount = 0;
    __syncthreads();

    // cooperative staging: threads 0..CH-1 check one face each, compact survivors
    if (tid < CH) {
        int m = blockIdx.z * CH + tid;   // M == SPLIT*CH == 2048
        float4 rb = bboxArr[m];
        bool pass = !(rb.x > txhi || rb.y < txlo || rb.z > tyhi || rb.w < tylo);
        if (pass) {
            int i = atomicAdd(&sCount, 1);
            sA[i]  = Aarr[m];
            sB[i]  = Barr[m];
            sRZ[i] = RZarr[m];
        }
    }
    __syncthreads();
    int cnt = sCount;

    if (h < HH) {
        int irow = SS - 1 - h;                       // vertical flip
        float XP = ((float)(2*w    + 1 - SS)) / (float)SS;
        float YP = ((float)(2*irow + 1 - SS)) / (float)SS;

        float depth = FARV;
        float sil = 0.0f;

        for (int k = 0; k < cnt; ++k) {
            float4 rA = sA[k];
            float4 rB = sB[k];
            float nx = XP - rB.x;
            float ny = YP - rB.y;
            float n0 = rA.x * nx + rA.y * ny;   // contract off: ref op order
            float n1 = rA.z * nx + rA.w * ny;
            float s  = rB.z;

            // conservative accept-on-doubt pre-test, folded to one compare.
            // |s| >= 1e-10 for staged faces, so multiplying the w2-margin
            // test through by |s| preserves it.
            float t0 = n0 * s;
            float t1 = n1 * s;
            float q  = s - n0 - n1;
            float mgn = fmaf(1e-5f, (fabsf(s) + fabsf(n0)) + fabsf(n1), 1e-30f);
            float t2 = fmaf(mgn, fabsf(s), q * s);
            if (fminf(fminf(t0, t1), t2) < 0.0f) continue;

            // decision-exact path: IEEE divides, ref op order
            float w0 = n0 / s;
            float w1 = n1 / s;
            float w2 = (1.0f - w0) - w1;
            if (!((w0 >= 0.0f) && (w1 >= 0.0f) && (w2 >= 0.0f))) continue;
            sil = 1.0f;
            // value-only math: rz precomputed, fma allowed, fast rcp.
            // accepted pixels have iz in [0.19, 1.03] -> guards can't flip.
            float4 rz = sRZ[k];
            float iz = fmaf(w2, rz.z, fmaf(w1, rz.y, w0 * rz.x));
            float zden = (fabsf(iz) > EPSV) ? iz : EPSV;
            float zp = __builtin_amdgcn_rcpf(zden);
            float zc = (zp > 0.0f) ? zp : FARV;
            depth = fminf(depth, zc);
        }

        // merge across face slices: positive floats are uint-monotone
        if (depth < FARV)
            atomicMin((unsigned int*)&out[h * WW + w], __float_as_uint(depth));
        if (sil > 0.0f)
            atomicMax((unsigned int*)&out[HH * WW + h * WW + w], __float_as_uint(sil));
    }
}

extern "C" void kernel_launch(void* const* d_in, const int* in_sizes, int n_in,
                              void* d_out, int out_size, void* d_ws, size_t ws_size,
                              hipStream_t stream) {
    const float* verts = (const float*)d_in[0];
    const int*   faces = (const int*)d_in[1];
    const float* K     = (const float*)d_in[2];
    const float* R     = (const float*)d_in[3];
    const float* t     = (const float*)d_in[4];
    float* out = (float*)d_out;

    int N = in_sizes[0] / 3;   // 8192
    int M = in_sizes[1] / 3;   // 2048

    char* ws = (char*)d_ws;
    float*  ndc  = (float*)ws;                 ws += (size_t)N * 3 * sizeof(float);
    float4* bbox = (float4*)ws;                ws += (size_t)M * sizeof(float4);
    float4* Aarr = (float4*)ws;                ws += (size_t)M * sizeof(float4);
    float4* Barr = (float4*)ws;                ws += (size_t)M * sizeof(float4);
    float4* RZarr= (float4*)ws;                ws += (size_t)M * sizeof(float4);

    xform_kernel<<<(N + 255) / 256, 256, 0, stream>>>(verts, K, R, t, ndc, N);
    face_init_kernel<<<(HH * WW + 255) / 256, 256, 0, stream>>>(
        ndc, faces, bbox, Aarr, Barr, RZarr, out, M);

    dim3 blk(16, 16);
    dim3 grd((WW + 15) / 16, (HH + 15) / 16, SPLIT);
    raster_kernel<<<grd, blk, 0, stream>>>(bbox, Aarr, Barr, RZarr, out, M);
}

// Round 4
// 100.527 us; speedup vs baseline: 6.1215x; 1.0692x over previous
//
#include <hip/hip_runtime.h>

#define SS 304
#define HH 228
#define WW 304
#define FARV 100.0f
#define EPSV 1e-07f
#define SPLIT 16         // face-range slices (gridDim.z)
#define CH 128           // faces per slice == one staging chunk

// per-vertex transform, bit-exact vs reference (contract off, IEEE divides)
__device__ __forceinline__ void xform_vertex(
    float u, float v, float d,
    float fx, float cx, float fy, float cy,
    float r00, float r01, float r02,
    float r10, float r11, float r12,
    float r20, float r21, float r22,
    float t0, float t1, float t2,
    float& xn, float& yn, float& z)
{
#pragma clang fp contract(off)
    float ki00 = 1.0f / fx;
    float ki02 = -(cx / fx);
    float ki11 = 1.0f / fy;
    float ki12 = -(cy / fy);
    float px = u * (float)WW;
    float py = v * (float)HH;
    float c0 = (ki00 * px + ki02) * d;
    float c1 = (ki11 * py + ki12) * d;
    float c2 = d;
    float e0 = ((r00*c0 + r01*c1) + r02*c2) + t0;
    float e1 = ((r10*c0 + r11*c1) + r12*c2) + t1;
    float e2 = ((r20*c0 + r21*c1) + r22*c2) + t2;
    z = e2;
    float zd = z + EPSV;
    float p0 = e0 / zd;
    float p1 = e1 / zd;
    float q0 = p0 * fx + cx;
    float q1 = p1 * fy + cy;
    float uu = q0 / (float)WW; uu = fminf(fmaxf(uu, 0.0f), 1.0f);
    float vv = q1 / (float)HH; vv = fminf(fmaxf(vv, 0.0f), 1.0f);
    xn = uu * (float)WW / (float)SS * 2.0f - 1.0f;
    yn = vv * (float)HH / (float)SS * 2.0f - 1.0f;
}

// ---- Kernel 1: out init + per-face vertex transform + precompute ----
__global__ __launch_bounds__(256) void prep_kernel(
    const float* __restrict__ verts,
    const int* __restrict__ faces,
    const float* __restrict__ Km,
    const float* __restrict__ Rm,
    const float* __restrict__ tm,
    float4* __restrict__ bboxArr,
    float4* __restrict__ Aarr,
    float4* __restrict__ Barr,
    float4* __restrict__ RZarr,
    float* __restrict__ out, int M)
{
#pragma clang fp contract(off)
    int g = blockIdx.x * blockDim.x + threadIdx.x;
    if (g < HH * WW) {
        out[g] = FARV;
        out[HH * WW + g] = 0.0f;
    }
    if (g >= M) return;
    int m = g;
    int i0 = faces[3*m+0], i1 = faces[3*m+1], i2 = faces[3*m+2];
    float fx = Km[0], cx = Km[2], fy = Km[4], cy = Km[5];
    float r00 = Rm[0], r01 = Rm[1], r02 = Rm[2];
    float r10 = Rm[3], r11 = Rm[4], r12 = Rm[5];
    float r20 = Rm[6], r21 = Rm[7], r22 = Rm[8];
    float t0 = tm[0], t1 = tm[1], t2 = tm[2];

    float x0, y0, z0, x1, y1, z1, x2, y2, z2;
    xform_vertex(verts[3*i0+0], verts[3*i0+1], verts[3*i0+2], fx,cx,fy,cy,
                 r00,r01,r02,r10,r11,r12,r20,r21,r22,t0,t1,t2, x0,y0,z0);
    xform_vertex(verts[3*i1+0], verts[3*i1+1], verts[3*i1+2], fx,cx,fy,cy,
                 r00,r01,r02,r10,r11,r12,r20,r21,r22,t0,t1,t2, x1,y1,z1);
    xform_vertex(verts[3*i2+0], verts[3*i2+1], verts[3*i2+2], fx,cx,fy,cy,
                 r00,r01,r02,r10,r11,r12,r20,r21,r22,t0,t1,t2, x2,y2,z2);

    float A0 = y1 - y2;
    float B0 = x2 - x1;
    float A1 = y2 - y0;
    float B1 = x0 - x2;
    float dy02 = y0 - y2;
    float denom = A0 * B1 + B0 * dy02;   // reference op order
    bool ok = fabsf(denom) > 1e-10f;
    float safe = ok ? denom : 1.0f;
    float xmin, xmax, ymin, ymax;
    if (ok) {
        xmin = fminf(x0, fminf(x1, x2)) - 1e-4f;
        xmax = fmaxf(x0, fmaxf(x1, x2)) + 1e-4f;
        ymin = fminf(y0, fminf(y1, y2)) - 1e-4f;
        ymax = fmaxf(y0, fmaxf(y1, y2)) + 1e-4f;
    } else {
        xmin = 1e30f; xmax = -1e30f; ymin = 1e30f; ymax = -1e30f;
    }
    bboxArr[m] = make_float4(xmin, xmax, ymin, ymax);
    Aarr[m]    = make_float4(A0, B0, A1, B1);
    Barr[m]    = make_float4(x2, y2, safe, 0.0f);
    RZarr[m]   = make_float4(1.0f / z0, 1.0f / z1, 1.0f / z2, 0.0f);
}

// ---- Kernel 2: rasterize (LDS-staged, face-sliced) ----
__global__ __launch_bounds__(256) void raster_kernel(
    const float4* __restrict__ bboxArr,
    const float4* __restrict__ Aarr,
    const float4* __restrict__ Barr,
    const float4* __restrict__ RZarr,
    float* __restrict__ out, int M)
{
#pragma clang fp contract(off)
    __shared__ float4 sA[CH];
    __shared__ float4 sB[CH];
    __shared__ float4 sRZ[CH];
    __shared__ int sCount;

    int tx = threadIdx.x, ty = threadIdx.y;
    int tid = ty * 16 + tx;
    int w = blockIdx.x * 16 + tx;
    int h = blockIdx.y * 16 + ty;

    int wlo = blockIdx.x * 16;
    int whi = min(wlo + 15, WW - 1);
    int hlo = blockIdx.y * 16;
    int hhi = min(hlo + 15, HH - 1);
    float txlo = ((float)(2*wlo + 1 - SS)) / (float)SS;
    float txhi = ((float)(2*whi + 1 - SS)) / (float)SS;
    float tylo = ((float)(2*(SS-1-hhi) + 1 - SS)) / (float)SS;
    float tyhi = ((float)(2*(SS-1-hlo) + 1 - SS)) / (float)SS;

    if (tid == 0) sCount = 0;
    __syncthreads();

    if (tid < CH) {
        int m = blockIdx.z * CH + tid;   // M == SPLIT*CH == 2048
        float4 rb = bboxArr[m];
        bool pass = !(rb.x > txhi || rb.y < txlo || rb.z > tyhi || rb.w < tylo);
        if (pass) {
            int i = atomicAdd(&sCount, 1);
            sA[i]  = Aarr[m];
            sB[i]  = Barr[m];
            sRZ[i] = RZarr[m];
        }
    }
    __syncthreads();
    int cnt = sCount;

    if (h < HH) {
        int irow = SS - 1 - h;
        float XP = ((float)(2*w    + 1 - SS)) / (float)SS;
        float YP = ((float)(2*irow + 1 - SS)) / (float)SS;

        float depth = FARV;
        float sil = 0.0f;

        for (int k = 0; k < cnt; ++k) {
            float4 rA = sA[k];
            float4 rB = sB[k];
            float nx = XP - rB.x;
            float ny = YP - rB.y;
            float n0 = rA.x * nx + rA.y * ny;   // contract off: ref op order
            float n1 = rA.z * nx + rA.w * ny;
            float s  = rB.z;

            // EXACT sign decisions for w0>=0 / w1>=0 (no divide needed):
            // s != 0, no NaN; n0/s rounds to -0 only if |n0| < 2^-150*|s|,
            // impossible by cancellation granularity -> sign test is exact.
            int sb = __float_as_int(s);
            bool ok0 = ((__float_as_int(n0) ^ sb) >= 0) || (n0 == 0.0f);
            bool ok1 = ((__float_as_int(n1) ^ sb) >= 0) || (n1 == 0.0f);

            // w2>=0: certainty band on q=(s-n0)-n1. |q| > band implies the
            // IEEE (1-n0/s)-n1/s has the same sign (20x rounding margin).
            float q  = (s - n0) - n1;
            float band = 1e-5f * ((fabsf(s) + fabsf(n0)) + fabsf(n1));
            float qs = (s >= 0.0f) ? q : -q;

            if (!(ok0 && ok1 && (qs >= -band))) continue;

            if (!(qs > band)) {
                // rare in-band case: exact IEEE re-check of w2 decision
                float w0e = n0 / s;
                float w1e = n1 / s;
                float w2e = (1.0f - w0e) - w1e;
                if (!(w2e >= 0.0f)) continue;
            }

            sil = 1.0f;
            // value-only path (threshold 2.0; rel err ~1e-6): rcp weights
            float4 rz = sRZ[k];
            float rs = __builtin_amdgcn_rcpf(s);
            float w0v = n0 * rs;
            float w1v = n1 * rs;
            float w2v = (1.0f - w0v) - w1v;
            float iz = fmaf(w2v, rz.z, fmaf(w1v, rz.y, w0v * rz.x));
            float zden = (fabsf(iz) > EPSV) ? iz : EPSV;
            float zp = __builtin_amdgcn_rcpf(zden);
            float zc = (zp > 0.0f) ? zp : FARV;
            depth = fminf(depth, zc);
        }

        // merge across face slices: positive floats are uint-monotone
        if (depth < FARV)
            atomicMin((unsigned int*)&out[h * WW + w], __float_as_uint(depth));
        if (sil > 0.0f)
            atomicMax((unsigned int*)&out[HH * WW + h * WW + w], __float_as_uint(sil));
    }
}

extern "C" void kernel_launch(void* const* d_in, const int* in_sizes, int n_in,
                              void* d_out, int out_size, void* d_ws, size_t ws_size,
                              hipStream_t stream) {
    const float* verts = (const float*)d_in[0];
    const int*   faces = (const int*)d_in[1];
    const float* K     = (const float*)d_in[2];
    const float* R     = (const float*)d_in[3];
    const float* t     = (const float*)d_in[4];
    float* out = (float*)d_out;

    int M = in_sizes[1] / 3;   // 2048

    char* ws = (char*)d_ws;
    float4* bbox = (float4*)ws;                ws += (size_t)M * sizeof(float4);
    float4* Aarr = (float4*)ws;                ws += (size_t)M * sizeof(float4);
    float4* Barr = (float4*)ws;                ws += (size_t)M * sizeof(float4);
    float4* RZarr= (float4*)ws;                ws += (size_t)M * sizeof(float4);

    prep_kernel<<<(HH * WW + 255) / 256, 256, 0, stream>>>(
        verts, faces, K, R, t, bbox, Aarr, Barr, RZarr, out, M);

    dim3 blk(16, 16);
    dim3 grd((WW + 15) / 16, (HH + 15) / 16, SPLIT);
    raster_kernel<<<grd, blk, 0, stream>>>(bbox, Aarr, Barr, RZarr, out, M);
}

// Round 5
// 90.210 us; speedup vs baseline: 6.8216x; 1.1144x over previous
//
#include <hip/hip_runtime.h>

#define SS 304
#define HH 228
#define WW 304
#define FARV 100.0f
#define EPSV 1e-07f
#define SPLIT 16         // face-range slices (gridDim.z)
#define CH 128           // faces per slice == one staging chunk

// per-vertex transform (contract off, IEEE divides — once per face, cheap)
__device__ __forceinline__ void xform_vertex(
    float u, float v, float d,
    float fx, float cx, float fy, float cy,
    float r00, float r01, float r02,
    float r10, float r11, float r12,
    float r20, float r21, float r22,
    float t0, float t1, float t2,
    float& xn, float& yn, float& z)
{
#pragma clang fp contract(off)
    float ki00 = 1.0f / fx;
    float ki02 = -(cx / fx);
    float ki11 = 1.0f / fy;
    float ki12 = -(cy / fy);
    float px = u * (float)WW;
    float py = v * (float)HH;
    float c0 = (ki00 * px + ki02) * d;
    float c1 = (ki11 * py + ki12) * d;
    float c2 = d;
    float e0 = ((r00*c0 + r01*c1) + r02*c2) + t0;
    float e1 = ((r10*c0 + r11*c1) + r12*c2) + t1;
    float e2 = ((r20*c0 + r21*c1) + r22*c2) + t2;
    z = e2;
    float zd = z + EPSV;
    float p0 = e0 / zd;
    float p1 = e1 / zd;
    float q0 = p0 * fx + cx;
    float q1 = p1 * fy + cy;
    float uu = q0 / (float)WW; uu = fminf(fmaxf(uu, 0.0f), 1.0f);
    float vv = q1 / (float)HH; vv = fminf(fmaxf(vv, 0.0f), 1.0f);
    xn = uu * (float)WW / (float)SS * 2.0f - 1.0f;
    yn = vv * (float)HH / (float)SS * 2.0f - 1.0f;
}

// ---- Kernel 1: out init + per-face vertex transform + plane precompute ----
// Per face we emit screen-space planes (sign-normalized so inside <=> >=0):
//   n0(X,Y) = A0*X + B0*Y + C0        (w0 numerator * sign(denom))
//   n1(X,Y) = A1*X + B1*Y + C1
//   n2      = |denom| - n0 - n1       (w2 numerator * sign(denom))
//   iz(X,Y) = E*X + F*Y + G           (interpolated 1/z — linear in X,Y)
__global__ __launch_bounds__(256) void prep_kernel(
    const float* __restrict__ verts,
    const int* __restrict__ faces,
    const float* __restrict__ Km,
    const float* __restrict__ Rm,
    const float* __restrict__ tm,
    float4* __restrict__ bboxArr,
    float4* __restrict__ G0arr,
    float4* __restrict__ G1arr,
    float2* __restrict__ G2arr,
    float* __restrict__ out, int M)
{
#pragma clang fp contract(off)
    int g = blockIdx.x * blockDim.x + threadIdx.x;
    if (g < HH * WW) {
        out[g] = FARV;
        out[HH * WW + g] = 0.0f;
    }
    if (g >= M) return;
    int m = g;
    int i0 = faces[3*m+0], i1 = faces[3*m+1], i2 = faces[3*m+2];
    float fx = Km[0], cx = Km[2], fy = Km[4], cy = Km[5];
    float r00 = Rm[0], r01 = Rm[1], r02 = Rm[2];
    float r10 = Rm[3], r11 = Rm[4], r12 = Rm[5];
    float r20 = Rm[6], r21 = Rm[7], r22 = Rm[8];
    float t0 = tm[0], t1 = tm[1], t2 = tm[2];

    float x0, y0, z0, x1, y1, z1, x2, y2, z2;
    xform_vertex(verts[3*i0+0], verts[3*i0+1], verts[3*i0+2], fx,cx,fy,cy,
                 r00,r01,r02,r10,r11,r12,r20,r21,r22,t0,t1,t2, x0,y0,z0);
    xform_vertex(verts[3*i1+0], verts[3*i1+1], verts[3*i1+2], fx,cx,fy,cy,
                 r00,r01,r02,r10,r11,r12,r20,r21,r22,t0,t1,t2, x1,y1,z1);
    xform_vertex(verts[3*i2+0], verts[3*i2+1], verts[3*i2+2], fx,cx,fy,cy,
                 r00,r01,r02,r10,r11,r12,r20,r21,r22,t0,t1,t2, x2,y2,z2);

    float A0 = y1 - y2;
    float B0 = x2 - x1;
    float A1 = y2 - y0;
    float B1 = x0 - x2;
    float dy02 = y0 - y2;
    float denom = A0 * B1 + B0 * dy02;
    bool ok = fabsf(denom) > 1e-10f;

    float xmin, xmax, ymin, ymax;
    if (ok) {
        xmin = fminf(x0, fminf(x1, x2)) - 1e-4f;
        xmax = fmaxf(x0, fmaxf(x1, x2)) + 1e-4f;
        ymin = fminf(y0, fminf(y1, y2)) - 1e-4f;
        ymax = fmaxf(y0, fmaxf(y1, y2)) + 1e-4f;
    } else {
        xmin = 1e30f; xmax = -1e30f; ymin = 1e30f; ymax = -1e30f;
    }
    bboxArr[m] = make_float4(xmin, xmax, ymin, ymax);

    float flip = (denom >= 0.0f) ? 1.0f : -1.0f;
    float sabs = fabsf(denom);
    float A0p = flip * A0, B0p = flip * B0;
    float C0p = -(A0p * x2 + B0p * y2);
    float A1p = flip * A1, B1p = flip * B1;
    float C1p = -(A1p * x2 + B1p * y2);
    float rz0 = 1.0f / z0, rz1 = 1.0f / z1, rz2 = 1.0f / z2;
    float D0 = rz0 / sabs, D1 = rz1 / sabs, D2 = rz2 / sabs;
    // iz = n0*D0 + n1*D1 + (sabs - n0 - n1)*D2  ->  plane E,F,G
    float d02 = D0 - D2, d12 = D1 - D2;
    float E = A0p * d02 + A1p * d12;
    float F = B0p * d02 + B1p * d12;
    float G = (C0p * d02 + C1p * d12) + sabs * D2;

    G0arr[m] = make_float4(A0p, B0p, C0p, sabs);
    G1arr[m] = make_float4(A1p, B1p, C1p, G);
    G2arr[m] = make_float2(E, F);
}

// ---- Kernel 2: rasterize (LDS-staged, face-sliced, branchless core) ----
__global__ __launch_bounds__(256) void raster_kernel(
    const float4* __restrict__ bboxArr,
    const float4* __restrict__ G0arr,
    const float4* __restrict__ G1arr,
    const float2* __restrict__ G2arr,
    float* __restrict__ out, int M)
{
    __shared__ float4 sG0[CH];
    __shared__ float4 sG1[CH];
    __shared__ float2 sG2[CH];
    __shared__ int sCount;

    int tx = threadIdx.x, ty = threadIdx.y;
    int tid = ty * 16 + tx;
    int w = blockIdx.x * 16 + tx;
    int h = blockIdx.y * 16 + ty;

    int wlo = blockIdx.x * 16;
    int whi = min(wlo + 15, WW - 1);
    int hlo = blockIdx.y * 16;
    int hhi = min(hlo + 15, HH - 1);
    float txlo = ((float)(2*wlo + 1 - SS)) / (float)SS;
    float txhi = ((float)(2*whi + 1 - SS)) / (float)SS;
    float tylo = ((float)(2*(SS-1-hhi) + 1 - SS)) / (float)SS;
    float tyhi = ((float)(2*(SS-1-hlo) + 1 - SS)) / (float)SS;

    if (tid == 0) sCount = 0;
    __syncthreads();

    if (tid < CH) {
        int m = blockIdx.z * CH + tid;   // M == SPLIT*CH == 2048
        float4 rb = bboxArr[m];
        bool pass = !(rb.x > txhi || rb.y < txlo || rb.z > tyhi || rb.w < tylo);
        if (pass) {
            int i = atomicAdd(&sCount, 1);
            sG0[i] = G0arr[m];
            sG1[i] = G1arr[m];
            sG2[i] = G2arr[m];
        }
    }
    __syncthreads();
    int cnt = sCount;

    if (h < HH) {
        int irow = SS - 1 - h;
        float XP = ((float)(2*w    + 1 - SS)) / (float)SS;
        float YP = ((float)(2*irow + 1 - SS)) / (float)SS;

        float mx = 0.0f;   // running max of interpolated 1/z over covering faces

        for (int k = 0; k < cnt; ++k) {
            float4 g0 = sG0[k];
            float4 g1 = sG1[k];
            float2 g2 = sG2[k];
            float n0 = fmaf(g0.x, XP, fmaf(g0.y, YP, g0.z));
            float n1 = fmaf(g1.x, XP, fmaf(g1.y, YP, g1.z));
            float n2 = (g0.w - n0) - n1;
            float iz = fmaf(g2.x, XP, fmaf(g2.y, YP, g1.w));
            float m3 = fminf(fminf(n0, n1), n2);
            float cand = (m3 >= 0.0f) ? iz : 0.0f;   // branchless accept
            mx = fmaxf(mx, cand);
        }

        // depth = 1/max(iz): rcp is monotone-decreasing on positives, so
        // min over faces of 1/iz == 1/(max iz). One rcp per pixel per slice.
        if (mx > 0.0f) {
            float depth = __builtin_amdgcn_rcpf(mx);
            atomicMin((unsigned int*)&out[h * WW + w], __float_as_uint(depth));
            atomicMax((unsigned int*)&out[HH * WW + h * WW + w],
                      __float_as_uint(1.0f));
        }
    }
}

extern "C" void kernel_launch(void* const* d_in, const int* in_sizes, int n_in,
                              void* d_out, int out_size, void* d_ws, size_t ws_size,
                              hipStream_t stream) {
    const float* verts = (const float*)d_in[0];
    const int*   faces = (const int*)d_in[1];
    const float* K     = (const float*)d_in[2];
    const float* R     = (const float*)d_in[3];
    const float* t     = (const float*)d_in[4];
    float* out = (float*)d_out;

    int M = in_sizes[1] / 3;   // 2048

    char* ws = (char*)d_ws;
    float4* bbox = (float4*)ws;                ws += (size_t)M * sizeof(float4);
    float4* G0   = (float4*)ws;                ws += (size_t)M * sizeof(float4);
    float4* G1   = (float4*)ws;                ws += (size_t)M * sizeof(float4);
    float2* G2   = (float2*)ws;                ws += (size_t)M * sizeof(float2);

    prep_kernel<<<(HH * WW + 255) / 256, 256, 0, stream>>>(
        verts, faces, K, R, t, bbox, G0, G1, G2, out, M);

    dim3 blk(16, 16);
    dim3 grd((WW + 15) / 16, (HH + 15) / 16, SPLIT);
    raster_kernel<<<grd, blk, 0, stream>>>(bbox, G0, G1, G2, out, M);
}